// Round 1
// 4323.894 us; speedup vs baseline: 1.0784x; 1.0784x over previous
//
#include <hip/hip_runtime.h>
#include <hip/hip_bf16.h>
#include <math.h>

// Problem constants
#define NTOK 1024          // Hp*Wp = 32*32
#define CDIM 768
#define BDIM 2
#define ROWS (BDIM*NTOK)   // 2048
#define NHEAD 12
#define HEADD 64
#define SCALE 0.125f       // 64^-0.5

__device__ __forceinline__ float us2f(unsigned short u) {
  return __uint_as_float(((unsigned int)u) << 16);
}
// dtype-flexible scalar load at ELEMENT index i: isbf ? bf16[i] : f32[i]
__device__ __forceinline__ float ldP(const void* p, size_t i, bool isbf) {
  return isbf ? us2f(((const unsigned short*)p)[i]) : ((const float*)p)[i];
}
__device__ __forceinline__ float4 ldP4(const void* p, size_t i, bool isbf) {
  if (isbf) {
    ushort4 u = *(const ushort4*)((const unsigned short*)p + i);
    return make_float4(us2f(u.x), us2f(u.y), us2f(u.z), us2f(u.w));
  }
  return *(const float4*)((const float*)p + i);
}

__device__ __forceinline__ float waveSum(float v) {
#pragma unroll
  for (int off = 32; off; off >>= 1) v += __shfl_xor(v, off, 64);
  return v;
}

// ---------------------------------------------------------------- dtype detector
// bf16 buffer of 0.02-scale gaussians: ~256/256 halfwords have sane exponent.
// f32 buffer: only odd halfwords do (~152/256 expected). Threshold 220 (≈15σ).
__global__ void detect_kernel(const void* __restrict__ probe, int* __restrict__ flag) {
  const unsigned short* u = (const unsigned short*)probe;
  int plaus = 0;
  for (int i = 0; i < 256; i++) {
    int e = (u[i] >> 7) & 0xFF;
    if (e >= 0x60 && e <= 0x8F) plaus++;
  }
  *flag = (plaus >= 220) ? 1 : 0;
}

// ---------------------------------------------------------------- im2col
__global__ __launch_bounds__(256) void im2col_kernel(const void* __restrict__ x,
                                                     float* __restrict__ col,
                                                     const int* __restrict__ dt) {
  bool isbf = (*dt != 0);
  int idx = blockIdx.x * 256 + threadIdx.x;     // < 2048*768
  int k = idx % 768;
  int row = idx / 768;
  int n = row & (NTOK - 1);
  int b = row >> 10;
  int ci = k >> 8;
  int rem = k & 255;
  int py = rem >> 4, px = rem & 15;
  int hp = n >> 5, wp = n & 31;
  int iy = hp * 16 + py, ix = wp * 16 + px;
  size_t xi = (((size_t)(b * 3 + ci) * 512) + iy) * 512 + ix;
  col[idx] = ldP(x, xi, isbf);
}

// ---------------------------------------------------------------- GEMM
// Y[m,n](ldy) (+)= A[m,k](lda, f32) @ W[wOff + n, k]^T + bias[bOff + n]
// flags: bit0 residual add, bit1 exact GELU
__global__ __launch_bounds__(256) void gemm_kernel(
    const float* __restrict__ A, int lda,
    const void* __restrict__ W, size_t wOff,
    const void* __restrict__ bias, size_t bOff,
    float* __restrict__ Y, int ldy,
    int Nout, int K, int flags, const int* __restrict__ dt) {
  bool isbf = (*dt != 0);
  __shared__ float As[16][64];
  __shared__ float Ws[16][64];
  int tid = threadIdx.x;
  int tx = tid & 15, ty = tid >> 4;
  int mbase = blockIdx.y * 64;
  int nbase = blockIdx.x * 64;
  int am = tid >> 2;               // 0..63
  int ak = (tid & 3) << 2;         // 0,4,8,12
  int gn = nbase + am;

  float acc[4][4];
#pragma unroll
  for (int i = 0; i < 4; i++)
#pragma unroll
    for (int j = 0; j < 4; j++) acc[i][j] = 0.f;

  for (int k0 = 0; k0 < K; k0 += 16) {
    float4 av = *(const float4*)(A + (size_t)(mbase + am) * lda + (k0 + ak));
    As[ak + 0][am] = av.x; As[ak + 1][am] = av.y;
    As[ak + 2][am] = av.z; As[ak + 3][am] = av.w;
    float4 wv = make_float4(0.f, 0.f, 0.f, 0.f);
    if (gn < Nout) wv = ldP4(W, wOff + (size_t)gn * K + (k0 + ak), isbf);
    Ws[ak + 0][am] = wv.x; Ws[ak + 1][am] = wv.y;
    Ws[ak + 2][am] = wv.z; Ws[ak + 3][am] = wv.w;
    __syncthreads();
#pragma unroll
    for (int kk = 0; kk < 16; kk++) {
      float4 a = *(const float4*)&As[kk][ty << 2];
      float4 w = *(const float4*)&Ws[kk][tx << 2];
      acc[0][0] += a.x * w.x; acc[0][1] += a.x * w.y; acc[0][2] += a.x * w.z; acc[0][3] += a.x * w.w;
      acc[1][0] += a.y * w.x; acc[1][1] += a.y * w.y; acc[1][2] += a.y * w.z; acc[1][3] += a.y * w.w;
      acc[2][0] += a.z * w.x; acc[2][1] += a.z * w.y; acc[2][2] += a.z * w.z; acc[2][3] += a.z * w.w;
      acc[3][0] += a.w * w.x; acc[3][1] += a.w * w.y; acc[3][2] += a.w * w.z; acc[3][3] += a.w * w.w;
    }
    __syncthreads();
  }

#pragma unroll
  for (int i = 0; i < 4; i++) {
    int m = mbase + (ty << 2) + i;
#pragma unroll
    for (int j = 0; j < 4; j++) {
      int n = nbase + (tx << 2) + j;
      if (n < Nout) {
        float v = acc[i][j];
        if (bias) v += ldP(bias, bOff + n, isbf);
        if (flags & 2) v = 0.5f * v * (1.0f + erff(v * 0.70710678118654752f));
        float* yp = Y + (size_t)m * ldy + n;
        if (flags & 1) v += *yp;
        *yp = v;
      }
    }
  }
}

// ---------------------------------------------------------------- LayerNorm
__global__ __launch_bounds__(256) void ln_kernel(const float* __restrict__ X,
                                                 const void* __restrict__ gs,
                                                 const void* __restrict__ gb,
                                                 size_t gOff,
                                                 float* __restrict__ H,
                                                 const int* __restrict__ dt) {
  bool isbf = (*dt != 0);
  int row = blockIdx.x;
  int tid = threadIdx.x;
  const float* xr = X + (size_t)row * CDIM;
  float v0 = xr[tid], v1 = xr[tid + 256], v2 = xr[tid + 512];
  float sum = waveSum(v0 + v1 + v2);
  __shared__ float red[4];
  __shared__ float statMu;
  __shared__ float statRs;
  int wid = tid >> 6, lane = tid & 63;
  if (lane == 0) red[wid] = sum;
  __syncthreads();
  if (tid == 0) statMu = (red[0] + red[1] + red[2] + red[3]) * (1.0f / 768.0f);
  __syncthreads();
  float mu = statMu;
  float d0 = v0 - mu, d1 = v1 - mu, d2 = v2 - mu;
  float sq = waveSum(d0 * d0 + d1 * d1 + d2 * d2);
  if (lane == 0) red[wid] = sq;
  __syncthreads();
  if (tid == 0)
    statRs = rsqrtf((red[0] + red[1] + red[2] + red[3]) * (1.0f / 768.0f) + 1e-6f);
  __syncthreads();
  float rs = statRs;
  float* hr = H + (size_t)row * CDIM;
  hr[tid]       = d0 * rs * ldP(gs, gOff + tid, isbf)       + ldP(gb, gOff + tid, isbf);
  hr[tid + 256] = d1 * rs * ldP(gs, gOff + tid + 256, isbf) + ldP(gb, gOff + tid + 256, isbf);
  hr[tid + 512] = d2 * rs * ldP(gs, gOff + tid + 512, isbf) + ldP(gb, gOff + tid + 512, isbf);
}

// ---------------------------------------------------------------- deformable attention (fused)
__global__ __launch_bounds__(256) void deform_kernel(const float* __restrict__ QKV,
                                                     const float* __restrict__ OFFS,
                                                     float* __restrict__ ATT) {
  int gid = blockIdx.x * 4 + (threadIdx.x >> 6);   // < 24576 = 2048*12
  int lane = threadIdx.x & 63;
  int h = gid % NHEAD;
  int bn = gid / NHEAD;          // b*1024 + n
  int n = bn & (NTOK - 1);
  int b = bn >> 10;
  int hp = n >> 5, wp = n & 31;

  float qd = QKV[(size_t)bn * 2304 + h * HEADD + lane];
  const float* orow = OFFS + (size_t)bn * 96 + h * 8;

  float sv[4], sc[4];
#pragma unroll
  for (int p = 0; p < 4; p++) {
    float ox = orow[p * 2 + 0];
    float oy = orow[p * 2 + 1];
    float xx = (float)wp + ox;     // sample pos in pixel coords (derived)
    float yy = (float)hp + oy;
    float x0f = floorf(xx), y0f = floorf(yy);
    int x0 = (int)x0f, y0 = (int)y0f;
    float wx = xx - x0f, wy = yy - y0f;
    int xs[2] = {x0, x0 + 1};
    int ys[2] = {y0, y0 + 1};
    float wxs[2] = {1.f - wx, wx};
    float wys[2] = {1.f - wy, wy};
    float skv = 0.f, svv = 0.f;
#pragma unroll
    for (int cy = 0; cy < 2; cy++) {
#pragma unroll
      for (int cx = 0; cx < 2; cx++) {
        int yi = ys[cy], xi = xs[cx];
        if (yi >= 0 && yi < 32 && xi >= 0 && xi < 32) {
          const float* kp = QKV + ((size_t)(b * NTOK + (yi << 5) + xi)) * 2304 + CDIM + h * HEADD + lane;
          float w = wys[cy] * wxs[cx];
          skv += w * kp[0];
          svv += w * kp[CDIM];
        }
      }
    }
    sv[p] = svv;
    sc[p] = waveSum(qd * skv) * SCALE;
  }
  float mx = fmaxf(fmaxf(sc[0], sc[1]), fmaxf(sc[2], sc[3]));
  float e0 = expf(sc[0] - mx), e1 = expf(sc[1] - mx), e2 = expf(sc[2] - mx), e3 = expf(sc[3] - mx);
  float l = e0 + e1 + e2 + e3;
  float od = (e0 * sv[0] + e1 * sv[1] + e2 * sv[2] + e3 * sv[3]) / l;
  ATT[(size_t)bn * CDIM + h * HEADD + lane] = od;
}

// ---------------------------------------------------------------- full attention (flash partial + combine)
// Restructured: thread = (query, 16-dim chunk). 4-thread groups share a query;
// scores reduced via 2x shfl_xor. q[16]+acc[16] => ~50 VGPR, no spill.
// Grid 768 = 2(b) * 12(h) * 2(kc: 512-key chunks) * 16(qb: 64-query tiles).
__global__ __launch_bounds__(256) void flash_partial(const float* __restrict__ QKV,
                                                     float* __restrict__ PACC,
                                                     float* __restrict__ PM,
                                                     float* __restrict__ PL) {
  int bid = blockIdx.x;                 // ((b*12+h)*2 + kc)*16 + qb
  int qb = bid & 15;
  int kc = (bid >> 4) & 1;
  int bh = bid >> 5;                    // 0..23 = b*12 + h
  int h = bh % NHEAD;
  int b = bh / NHEAD;
  int tid = threadIdx.x;
  int qi = tid >> 2;                    // 0..63 query within tile
  int dc = (tid & 3) << 4;              // 0,16,32,48 dim-chunk base
  int n = qb * 64 + qi;

  const float* base = QKV + (size_t)b * NTOK * 2304;
  float q[16];
  const float* qp = base + (size_t)n * 2304 + h * HEADD + dc;
#pragma unroll
  for (int j = 0; j < 4; j++) {
    float4 t = *(const float4*)(qp + 4 * j);
    q[4 * j] = t.x; q[4 * j + 1] = t.y; q[4 * j + 2] = t.z; q[4 * j + 3] = t.w;
  }
  float acc[16];
#pragma unroll
  for (int j = 0; j < 16; j++) acc[j] = 0.f;
  float mrun = -INFINITY, l = 0.f;

  __shared__ float Ks[64][68];   // +4 pad: staging writes 32-way -> 4-way conflict
  __shared__ float Vs[64][68];

  for (int kt = 0; kt < 8; kt++) {
    int mk = kc * 512 + kt * 64;
    {
      int krow = tid >> 2;
      int d0 = (tid & 3) << 4;
      const float* kp = base + (size_t)(mk + krow) * 2304 + CDIM + h * HEADD + d0;
#pragma unroll
      for (int j = 0; j < 4; j++)
        *(float4*)&Ks[krow][d0 + 4 * j] = *(const float4*)(kp + 4 * j);
      const float* vp = kp + CDIM;
#pragma unroll
      for (int j = 0; j < 4; j++)
        *(float4*)&Vs[krow][d0 + 4 * j] = *(const float4*)(vp + 4 * j);
    }
    __syncthreads();
    for (int m = 0; m < 64; m++) {
      const float* kr = &Ks[m][dc];
      float s0 = 0.f, s1 = 0.f, s2 = 0.f, s3 = 0.f;
#pragma unroll
      for (int j = 0; j < 4; j++) {
        s0 += q[4 * j + 0] * kr[4 * j + 0];
        s1 += q[4 * j + 1] * kr[4 * j + 1];
        s2 += q[4 * j + 2] * kr[4 * j + 2];
        s3 += q[4 * j + 3] * kr[4 * j + 3];
      }
      float s = (s0 + s1) + (s2 + s3);
      s += __shfl_xor(s, 1, 64);        // reduce across the 4-lane dim group
      s += __shfl_xor(s, 2, 64);
      s *= SCALE;
      const float* vr = &Vs[m][dc];
      if (s <= mrun) {                  // common path: no new max, no rescale
        float p = __expf(s - mrun);
        l += p;
#pragma unroll
        for (int j = 0; j < 16; j++) acc[j] = fmaf(p, vr[j], acc[j]);
      } else {                          // rare: new max -> rescale (p == 1)
        float alpha = __expf(mrun - s);
        l = fmaf(l, alpha, 1.f);
#pragma unroll
        for (int j = 0; j < 16; j++) acc[j] = fmaf(acc[j], alpha, vr[j]);
        mrun = s;
      }
    }
    __syncthreads();
  }

  size_t idx = (size_t)(bh * 2 + kc) * NTOK + n;
  if ((tid & 3) == 0) {
    PM[idx] = mrun;
    PL[idx] = l;
  }
  float* ap = PACC + idx * 64 + dc;
#pragma unroll
  for (int j = 0; j < 4; j++) {
    float4 t;
    t.x = acc[4 * j]; t.y = acc[4 * j + 1]; t.z = acc[4 * j + 2]; t.w = acc[4 * j + 3];
    *(float4*)(ap + 4 * j) = t;
  }
}

__global__ __launch_bounds__(256) void flash_combine(const float* __restrict__ PACC,
                                                     const float* __restrict__ PM,
                                                     const float* __restrict__ PL,
                                                     float* __restrict__ ATT) {
  int gid = blockIdx.x * 4 + (threadIdx.x >> 6);   // bh*1024 + n, total 24576
  int lane = threadIdx.x & 63;
  int n = gid & (NTOK - 1);
  int bh = gid >> 10;                               // b*12 + h
  size_t base = (size_t)bh * 2048 + n;              // 2 partials per bh
  float m0 = PM[base], m1 = PM[base + 1024];
  float mx = fmaxf(m0, m1);
  float w0 = __expf(m0 - mx), w1 = __expf(m1 - mx);
  float l = w0 * PL[base] + w1 * PL[base + 1024];
  float a = w0 * PACC[base * 64 + lane] + w1 * PACC[(base + 1024) * 64 + lane];
  int b = bh / NHEAD, h = bh - b * NHEAD;
  ATT[((size_t)(b * NTOK + n)) * CDIM + h * HEADD + lane] = a / l;
}

// ---------------------------------------------------------------- output transpose (B,N,C)->(B,C,N)
__global__ __launch_bounds__(256) void out_kernel(const float* __restrict__ X,
                                                  void* __restrict__ out,
                                                  const int* __restrict__ dt) {
  bool isbf = (*dt != 0);
  int idx = blockIdx.x * 256 + threadIdx.x;   // < 2*768*1024
  int n = idx & (NTOK - 1);
  int rest = idx >> 10;
  int c = rest % CDIM;
  int b = rest / CDIM;
  float v = X[((size_t)(b * NTOK + n)) * CDIM + c];
  if (isbf)
    ((__hip_bfloat16*)out)[idx] = __float2bfloat16(v);
  else
    ((float*)out)[idx] = v;
}

// ---------------------------------------------------------------- launch
extern "C" void kernel_launch(void* const* d_in, const int* in_sizes, int n_in,
                              void* d_out, int out_size, void* d_ws, size_t ws_size,
                              hipStream_t stream) {
  const void* x       = d_in[0];
  const void* patch_w = d_in[1];
  const void* patch_b = d_in[2];
  const void* ln1_s   = d_in[3];
  const void* ln1_b   = d_in[4];
  const void* qkv_w   = d_in[5];
  const void* offs_w  = d_in[6];
  const void* offs_b  = d_in[7];
  const void* proj_w  = d_in[8];
  const void* proj_b  = d_in[9];
  const void* ln2_s   = d_in[10];
  const void* ln2_b   = d_in[11];
  const void* fc1_w   = d_in[12];
  const void* fc1_b   = d_in[13];
  const void* fc2_w   = d_in[14];
  const void* fc2_b   = d_in[15];

  float* W = (float*)d_ws;
  const size_t XSZ = (size_t)ROWS * CDIM;        // 1,572,864
  float* X    = W;                               // residual stream
  float* Hb   = W + XSZ;                         // LN output
  float* ATT  = W + 2 * XSZ;                     // attention output
  float* QKV  = W + 3 * XSZ;                     // 2048 x 2304 (also im2col scratch)
  float* BIG  = W + 3 * XSZ + (size_t)ROWS * 2304;  // 2048 x 3072 (fc1 hidden / flash PACC)
  float* OFFS = BIG + (size_t)ROWS * 3072;       // 2048 x 96 (also flash PM/PL region)
  float* PM = OFFS;
  float* PL = OFFS + 24 * 4 * NTOK;              // 98,304 (only 49,152 used now)
  int* FLAG = (int*)(OFFS + 196608);

  detect_kernel<<<1, 1, 0, stream>>>(qkv_w, FLAG);

  // patch embed: im2col -> GEMM
  im2col_kernel<<<6144, 256, 0, stream>>>(x, QKV, FLAG);
  gemm_kernel<<<dim3(12, 32), 256, 0, stream>>>(QKV, 768, patch_w, 0, patch_b, 0,
                                                X, 768, 768, 768, 0, FLAG);

  for (int i = 0; i < 6; i++) {
    ln_kernel<<<2048, 256, 0, stream>>>(X, ln1_s, ln1_b, (size_t)i * CDIM, Hb, FLAG);
    gemm_kernel<<<dim3(36, 32), 256, 0, stream>>>(Hb, 768, qkv_w, (size_t)i * 2304 * 768,
                                                  nullptr, 0, QKV, 2304, 2304, 768, 0, FLAG);
    if ((i + 1) % 3 != 0) {
      gemm_kernel<<<dim3(2, 32), 256, 0, stream>>>(QKV, 2304, offs_w, (size_t)i * 96 * 768,
                                                   offs_b, (size_t)i * 96, OFFS, 96, 96, 768, 0, FLAG);
      deform_kernel<<<6144, 256, 0, stream>>>(QKV, OFFS, ATT);
    } else {
      flash_partial<<<768, 256, 0, stream>>>(QKV, BIG, PM, PL);
      flash_combine<<<6144, 256, 0, stream>>>(BIG, PM, PL, ATT);
    }
    gemm_kernel<<<dim3(12, 32), 256, 0, stream>>>(ATT, 768, proj_w, (size_t)i * 768 * 768,
                                                  proj_b, (size_t)i * CDIM, X, 768, 768, 768, 1, FLAG);
    ln_kernel<<<2048, 256, 0, stream>>>(X, ln2_s, ln2_b, (size_t)i * CDIM, Hb, FLAG);
    gemm_kernel<<<dim3(48, 32), 256, 0, stream>>>(Hb, 768, fc1_w, (size_t)i * 3072 * 768,
                                                  fc1_b, (size_t)i * 3072, BIG, 3072, 3072, 768, 2, FLAG);
    gemm_kernel<<<dim3(12, 32), 256, 0, stream>>>(BIG, 3072, fc2_w, (size_t)i * 768 * 3072,
                                                  fc2_b, (size_t)i * CDIM, X, 768, 768, 3072, 1, FLAG);
  }

  out_kernel<<<6144, 256, 0, stream>>>(X, d_out, FLAG);
}